// Round 4
// baseline (141.741 us; speedup 1.0000x reference)
//
#include <hip/hip_runtime.h>
#include <hip/hip_bf16.h>

// Problem constants
#define BB 4
#define NN 2048
#define DD 64
#define HH 8
#define DHH 512  // D*H

typedef __bf16 bf16_t;
typedef __bf16 bf16x8 __attribute__((ext_vector_type(8)));
typedef __bf16 bf16x4 __attribute__((ext_vector_type(4)));
typedef float f32x4 __attribute__((ext_vector_type(4)));
typedef long long i64;
typedef i64 i64x2 __attribute__((ext_vector_type(2)));
typedef _Float16 f16_t;
typedef _Float16 f16x4 __attribute__((ext_vector_type(4)));
typedef __fp16 h16x2 __attribute__((ext_vector_type(2)));   // cvt_pkrtz native type

// Async global->LDS, 16B per lane. HW places lane i at (wave-uniform base) + i*16.
__device__ __forceinline__ void dma16(const void* g, void* l) {
    __builtin_amdgcn_global_load_lds(
        (const __attribute__((address_space(1))) unsigned int*)g,
        (__attribute__((address_space(3))) unsigned int*)l,
        16, 0, 0);
}

#define MFMA   __builtin_amdgcn_mfma_f32_16x16x32_bf16
#define MFMA8  __builtin_amdgcn_mfma_f32_16x16x32_fp8_fp8
#define MFMA16F __builtin_amdgcn_mfma_f32_16x16x16f16

// q-scale 1/sqrt(64) with log2(e) folded in (softmax via exp2)
#define QSCALE 0.18033688011112042f

// fp8 q/k row layout (64 bytes per (b,h,n)): logical element d lives at byte
//   phys(d) = (d&7) + (d>>5)*8 + (((d>>3)&3) ^ swz2(n))*16,  swz2(n) = (n&3)^((n>>2)&3)
// One b128 read at granule (quad ^ swz2(n)) yields BOTH K=32 fp8 MFMA frags
// (i64x2: .x = k-lo, .y = k-hi).
//
// vt layout: key-block-major f16 [b, h, n>>4, d, n&15] — a wave's per-tile V
// slice (64 d x 16 keys = 2KB) is CONTIGUOUS in global. flash reads K/V
// fragments DIRECTLY global->VGPR, triple-buffered (R4): load-to-use spans
// two full tile bodies (~400+ cy) > L2 latency -> stalls covered. No LDS /
// barriers / manual waitcnt in the main loop.

// -------------------------------------------------------------------------
// Kernel P: prep (unchanged). Wqt/Wkt/Wvt [512][64] bf16 (QSCALE in Wqt),
// Wut [64][512] bf16. 16 blocks.
// -------------------------------------------------------------------------
__global__ __launch_bounds__(256) void prep(
    const float* __restrict__ Wq, const float* __restrict__ Wk,
    const float* __restrict__ Wv, const float* __restrict__ Wu,
    bf16_t* __restrict__ Wqt, bf16_t* __restrict__ Wkt,
    bf16_t* __restrict__ Wvt, bf16_t* __restrict__ Wut)
{
    const int bid = blockIdx.x, tid = threadIdx.x;
    if (bid < 12) {
        const int m = bid >> 2, slice = bid & 3;
        const float* src = (m == 0) ? Wq : (m == 1) ? Wk : Wv;
        bf16_t* dst = (m == 0) ? Wqt : (m == 1) ? Wkt : Wvt;
        const float scale = (m == 0) ? QSCALE : 1.0f;
        const int dc = slice * 128 + (tid >> 1);
        const int kbase = (tid & 1) * 32;
        #pragma unroll
        for (int k0 = 0; k0 < 4; ++k0) {
            bf16x8 p;
            #pragma unroll
            for (int j = 0; j < 8; ++j)
                p[j] = (bf16_t)(src[(size_t)(kbase + k0 * 8 + j) * 512 + dc] * scale);
            *(bf16x8*)(dst + dc * 64 + kbase + k0 * 8) = p;
        }
    } else {
        const int kq = (bid - 12) * 128;
        const int dc = tid >> 2, sub = (tid & 3) * 32;
        #pragma unroll
        for (int k0 = 0; k0 < 4; ++k0) {
            bf16x8 p;
            #pragma unroll
            for (int j = 0; j < 8; ++j)
                p[j] = (bf16_t)Wu[(size_t)(kq + sub + k0 * 8 + j) * 64 + dc];
            *(bf16x8*)(Wut + dc * 512 + kq + sub + k0 * 8) = p;
        }
    }
}

// -------------------------------------------------------------------------
// Kernel A: QKV via MFMA (unchanged — verified). q,k -> fp8 e4m3 packed
// layout (widened swz2); vt -> f16 key-block-major.
// -------------------------------------------------------------------------
__global__ __launch_bounds__(256) void qkv_mfma(
    const float* __restrict__ x, const bf16_t* __restrict__ Wqt,
    const bf16_t* __restrict__ Wkt, const bf16_t* __restrict__ Wvt,
    char* __restrict__ q8, char* __restrict__ k8, f16_t* __restrict__ vt)
{
    const int n0   = blockIdx.x * 64;
    const int h    = blockIdx.y;
    const int tid  = threadIdx.x;
    const int w    = tid >> 6;
    const int lane = tid & 63;
    const int quad = lane >> 4;
    const int c    = lane & 15;
    const int cq   = c & 7;
    const int l8   = lane >> 3;
    const int lg   = (lane & 7) ^ l8;
    const int lo   = l8 * 128 + lg * 16;
    const int sw0  = ((quad    ) ^ cq) * 16;
    const int sw1  = ((quad + 4) ^ cq) * 16;
    const int w2048 = w * 2048;

    __shared__ __align__(16) float  xs[64 * 64];   // 16KB [row][256B], swizzled
    __shared__ __align__(16) bf16_t Wqs[64 * 64], Wks[64 * 64], Wvs[64 * 64];

    {
        const int rloc = lane >> 4;
        const int s    = lane & 15;
        #pragma unroll
        for (int j = 0; j < 4; ++j) {
            int chunk = w * 4 + j;
            int r7 = (chunk * 4 + rloc) & 7;
            const char* src = (const char*)(x + (size_t)(n0 + chunk * 4 + rloc) * 64)
                            + ((s & 8) | ((s & 7) ^ r7)) * 16;
            dma16(src, (char*)xs + chunk * 1024);
        }
    }
    const char* qg = (const char*)Wqt + (size_t)h * 8192;
    const char* kg = (const char*)Wkt + (size_t)h * 8192;
    const char* vg = (const char*)Wvt + (size_t)h * 8192;
    dma16(qg + w2048 + lo,        (char*)Wqs + w2048);
    dma16(qg + w2048 + 1024 + lo, (char*)Wqs + w2048 + 1024);
    dma16(kg + w2048 + lo,        (char*)Wks + w2048);
    dma16(kg + w2048 + 1024 + lo, (char*)Wks + w2048 + 1024);
    dma16(vg + w2048 + lo,        (char*)Wvs + w2048);
    dma16(vg + w2048 + 1024 + lo, (char*)Wvs + w2048 + 1024);
    __syncthreads();

    auto xfrag = [&](int row, int kk) -> bf16x8 {
        const char* rbase = (const char*)xs + row * 256;
        int g0 = kk * 8 + ((quad * 2    ) ^ cq);
        int g1 = kk * 8 + ((quad * 2 + 1) ^ cq);
        f32x4 a = *(const f32x4*)(rbase + g0 * 16);
        f32x4 b = *(const f32x4*)(rbase + g1 * 16);
        bf16x8 r;
        r[0] = (bf16_t)a[0]; r[1] = (bf16_t)a[1]; r[2] = (bf16_t)a[2]; r[3] = (bf16_t)a[3];
        r[4] = (bf16_t)b[0]; r[5] = (bf16_t)b[1]; r[6] = (bf16_t)b[2]; r[7] = (bf16_t)b[3];
        return r;
    };

    bf16x8 xf0 = xfrag(w * 16 + c, 0);
    bf16x8 xf1 = xfrag(w * 16 + c, 1);

    const int gr = n0 + w * 16 + c;
    const int bb = gr >> 11, nn = gr & 2047;
    char* qrow_g = q8 + (((size_t)bb * HH + h) * NN + nn) * 64;
    char* krow_g = k8 + (((size_t)bb * HH + h) * NN + nn) * 64;
    const int nsw = (nn & 3) ^ ((nn >> 2) & 3);   // widened granule swizzle

    #pragma unroll
    for (int mb = 0; mb < 4; ++mb) {
        const char* aq = (const char*)Wqs + (mb * 16 + c) * 128;
        const char* ak = (const char*)Wks + (mb * 16 + c) * 128;
        f32x4 accq = (f32x4){0.f, 0.f, 0.f, 0.f};
        f32x4 acck = (f32x4){0.f, 0.f, 0.f, 0.f};
        accq = MFMA(*(const bf16x8*)(aq + sw0), xf0, accq, 0, 0, 0);
        accq = MFMA(*(const bf16x8*)(aq + sw1), xf1, accq, 0, 0, 0);
        acck = MFMA(*(const bf16x8*)(ak + sw0), xf0, acck, 0, 0, 0);
        acck = MFMA(*(const bf16x8*)(ak + sw1), xf1, acck, 0, 0, 0);
        int g2  = (mb * 2 + (quad >> 1)) & 3;
        int off = ((quad & 1) * 4) + ((mb >> 1) * 8) + ((g2 ^ nsw) * 16);
        int pq = __builtin_amdgcn_cvt_pk_fp8_f32(accq[0], accq[1], 0, false);
        pq     = __builtin_amdgcn_cvt_pk_fp8_f32(accq[2], accq[3], pq, true);
        int pk = __builtin_amdgcn_cvt_pk_fp8_f32(acck[0], acck[1], 0, false);
        pk     = __builtin_amdgcn_cvt_pk_fp8_f32(acck[2], acck[3], pk, true);
        *(int*)(qrow_g + off) = pq;
        *(int*)(krow_g + off) = pk;
    }

    const char* wvrow = (const char*)Wvs + (w * 16 + c) * 128;
    bf16x8 vf0 = *(const bf16x8*)(wvrow + sw0);
    bf16x8 vf1 = *(const bf16x8*)(wvrow + sw1);

    const int bb2 = n0 >> 11;
    // key-block-major vt: ((n>>4)*64 + d)*16 + (n&15), d = w*16+c
    f16_t* vtb = vt + ((size_t)bb2 * HH + h) * (size_t)(DD * NN)
               + (size_t)((n0 & 2047) >> 4) * 1024 + (w * 16 + c) * 16 + quad * 4;

    #pragma unroll
    for (int nb = 0; nb < 4; ++nb) {
        f32x4 acc = (f32x4){0.f, 0.f, 0.f, 0.f};
        acc = MFMA(xfrag(nb * 16 + c, 0), vf0, acc, 0, 0, 0);
        acc = MFMA(xfrag(nb * 16 + c, 1), vf1, acc, 0, 0, 0);
        f16x4 p = { (f16_t)acc[0], (f16_t)acc[1], (f16_t)acc[2], (f16_t)acc[3] };
        *(f16x4*)(vtb + nb * 1024) = p;
    }
}

// -------------------------------------------------------------------------
// Kernel B: flash attention — direct global->VGPR operand fetch, no LDS in
// the main loop. R4: TRIPLE-buffered register sets (A/B/C) — load issued
// 3 tiles ahead of use, consumed 2 full bodies later (~400+ cy) > L2-hit
// latency -> latency-bound stall (R3: MfmaUtil 31%, both-low) removed.
// Correctness = plain register load deps (compiler-inserted waits);
// deterministic, no LDS hazards, no barriers until the epilogue.
// -------------------------------------------------------------------------
__global__ __launch_bounds__(256, 3) void flash_attn(
    const char* __restrict__ q8, const char* __restrict__ k8,
    const f16_t* __restrict__ vt, bf16_t* __restrict__ y)
{
    const int h    = blockIdx.x;          // head first -> XCD L2 locality
    const int n0   = blockIdx.y * 64;
    const int b    = blockIdx.z;
    const int tid  = threadIdx.x;
    const int w    = tid >> 6;
    const int lane = tid & 63;
    const int quad = lane >> 4;
    const int c    = lane & 15;
    const int ksw  = (quad ^ (c & 3) ^ ((c >> 2) & 3)) * 16;  // fp8 granule swz

    __shared__ __align__(16) char SM[17408];   // epilogue only: Ob 16K + Lb 1K

    const size_t bh = (size_t)(b * HH + h);
    const char* qp = q8 + bh * (size_t)(NN * 64);
    const char* kp = k8 + bh * (size_t)(NN * 64);
    const char* vp = (const char*)(vt + bh * (size_t)(DD * NN));

    // Q B-frags (fp8 packed)
    i64x2 qf[4];
    #pragma unroll
    for (int cb = 0; cb < 4; ++cb)
        qf[cb] = *(const i64x2*)(qp + (size_t)(n0 + cb * 16 + c) * 64 + ksw);

    // Per-lane direct fragment pointers.
    // K frag for tile t: key row (t*64 + w*16 + c), granule ksw.
    const char* kglob = kp + w * 1024 + (size_t)c * 64 + ksw;     // + t*4096
    // V frag db for tile t: key-block (t*4+w), d = db*16+c, keys quad*4..+3.
    const char* vglob = vp + w * 2048 + (size_t)c * 32 + quad * 8; // + t*8192 + db*512

    f32x4 lsum4[4];
    f32x4 o[4][4];   // o[db][cb]: O^T[d=db*16+quad*4+r][q=cb*16+c]
    #pragma unroll
    for (int cb = 0; cb < 4; ++cb) lsum4[cb] = (f32x4){0.f, 0.f, 0.f, 0.f};
    #pragma unroll
    for (int db = 0; db < 4; ++db)
        #pragma unroll
        for (int cb = 0; cb < 4; ++cb) o[db][cb] = (f32x4){0.f, 0.f, 0.f, 0.f};

    #define LOADT(kf_, vf_, t) do {                                         \
        const char* kg_ = kglob + (size_t)(t) * 4096;                       \
        const char* vg_ = vglob + (size_t)(t) * 8192;                       \
        kf_     = *(const i64x2*)(kg_);                                     \
        vf_[0]  = *(const f16x4*)(vg_);                                     \
        vf_[1]  = *(const f16x4*)(vg_ + 512);                               \
        vf_[2]  = *(const f16x4*)(vg_ + 1024);                              \
        vf_[3]  = *(const f16x4*)(vg_ + 1536);                              \
    } while (0)

    #define BODYR(kf_, vf_) do {                                            \
        _Pragma("unroll")                                                   \
        for (int cb = 0; cb < 4; ++cb) {                                    \
            f32x4 s_ = (f32x4){0.f, 0.f, 0.f, 0.f};                         \
            s_ = MFMA8(kf_.x, qf[cb].x, s_, 0, 0, 0);                       \
            s_ = MFMA8(kf_.y, qf[cb].y, s_, 0, 0, 0);                       \
            float p0_ = __builtin_amdgcn_exp2f(s_[0]);                      \
            float p1_ = __builtin_amdgcn_exp2f(s_[1]);                      \
            float p2_ = __builtin_amdgcn_exp2f(s_[2]);                      \
            float p3_ = __builtin_amdgcn_exp2f(s_[3]);                      \
            lsum4[cb] += (f32x4){p0_, p1_, p2_, p3_};                       \
            h16x2 ab_ = __builtin_amdgcn_cvt_pkrtz(p0_, p1_);               \
            h16x2 cd_ = __builtin_amdgcn_cvt_pkrtz(p2_, p3_);               \
            f16x4 pf_;                                                      \
            __builtin_memcpy(&pf_, &ab_, 4);                                \
            __builtin_memcpy((char*)&pf_ + 4, &cd_, 4);                     \
            _Pragma("unroll")                                               \
            for (int db = 0; db < 4; ++db)                                  \
                o[db][cb] = MFMA16F(vf_[db], pf_, o[db][cb], 0, 0, 0);      \
        }                                                                   \
    } while (0)

    i64x2 kA, kB, kC;
    f16x4 vA[4], vB[4], vC[4];
    LOADT(kA, vA, 0);
    LOADT(kB, vB, 1);
    LOADT(kC, vC, 2);

    #pragma unroll 1
    for (int j = 0; j < 10; ++j) {
        const int t = j * 3;
        const int ta = (t + 3 < 32) ? t + 3 : 31;
        const int tb = (t + 4 < 32) ? t + 4 : 31;
        const int tc = (t + 5 < 32) ? t + 5 : 31;
        BODYR(kA, vA); LOADT(kA, vA, ta);   // body t,   refill A (use at t+3)
        BODYR(kB, vB); LOADT(kB, vB, tb);   // body t+1
        BODYR(kC, vC); LOADT(kC, vC, tc);   // body t+2
    }
    BODYR(kA, vA);   // tile 30
    BODYR(kB, vB);   // tile 31 (C's tail dup-load unused)

    #undef LOADT
    #undef BODYR

    // horizontal lsum
    float lsum[4];
    #pragma unroll
    for (int cb = 0; cb < 4; ++cb)
        lsum[cb] = (lsum4[cb][0] + lsum4[cb][1]) + (lsum4[cb][2] + lsum4[cb][3]);

    // ---- epilogue: cross-wave reduction (Ob = SM[0..16K), Lb = SM+16K) ----
    char*  Ob = SM;
    float* Lb = (float*)(SM + 16384);

    #pragma unroll
    for (int cb = 0; cb < 4; ++cb) {
        lsum[cb] += __shfl_xor(lsum[cb], 16, 64);
        lsum[cb] += __shfl_xor(lsum[cb], 32, 64);
    }
    if (quad == 0) {
        #pragma unroll
        for (int cb = 0; cb < 4; ++cb)
            Lb[(w * 4 + cb) * 16 + c] = lsum[cb];
    }

    // O: sequential accumulate across waves
    #pragma unroll
    for (int ww = 0; ww < 4; ++ww) {
        if (w == ww) {
            #pragma unroll
            for (int db = 0; db < 4; ++db) {
                #pragma unroll
                for (int cb = 0; cb < 4; ++cb) {
                    char* p = Ob + (size_t)(((db * 4 + cb) * 4 + quad) * 16 + c) * 16;
                    f32x4 v = o[db][cb];
                    if (ww > 0) v += *(const f32x4*)p;
                    *(f32x4*)p = v;
                }
            }
        }
        __syncthreads();
    }

    // readout: thread t -> q-row n_loc = t&63, d-quarter dq = t>>6
    {
        const int n_loc = tid & 63;
        const int dq    = tid >> 6;
        const int qcb   = n_loc >> 4;
        const int cc    = n_loc & 15;
        float l = Lb[(0 * 4 + qcb) * 16 + cc] + Lb[(1 * 4 + qcb) * 16 + cc]
                + Lb[(2 * 4 + qcb) * 16 + cc] + Lb[(3 * 4 + qcb) * 16 + cc];
        float inv = 1.0f / l;
        float vals[16];
        #pragma unroll
        for (int q2 = 0; q2 < 4; ++q2) {
            f32x4 v = *(const f32x4*)(Ob
                    + (size_t)(((dq * 4 + qcb) * 4 + q2) * 16 + cc) * 16);
            vals[q2 * 4 + 0] = v[0]; vals[q2 * 4 + 1] = v[1];
            vals[q2 * 4 + 2] = v[2]; vals[q2 * 4 + 3] = v[3];
        }
        bf16x8 o0, o1;
        #pragma unroll
        for (int j = 0; j < 8; ++j) {
            o0[j] = (bf16_t)(vals[j] * inv);
            o1[j] = (bf16_t)(vals[8 + j] * inv);
        }
        bf16_t* yrow = y + bh * (size_t)(NN * DD) + (size_t)(n0 + n_loc) * DD + dq * 16;
        *(bf16x8*)(yrow)     = o0;
        *(bf16x8*)(yrow + 8) = o1;
    }
}

// -------------------------------------------------------------------------
// Kernel C: output projection via MFMA (unchanged). 512 blocks.
// -------------------------------------------------------------------------
__global__ __launch_bounds__(256) void out_proj(
    const bf16_t* __restrict__ y,    // [b,h,n,d] bf16
    const bf16_t* __restrict__ Wut,  // [64][512]
    const float* __restrict__ bu, float* __restrict__ out)
{
    const int rt   = blockIdx.x >> 1;
    const int dh   = blockIdx.x & 1;
    const int row0 = rt * 32;
    const int b    = row0 >> 11;
    const int nn0  = row0 & 2047;
    const int tid  = threadIdx.x;
    const int w    = tid >> 6;
    const int lane = tid & 63;
    const int quad = lane >> 4;
    const int c    = lane & 15;
    const int cq   = c & 7;

    __shared__ __align__(16) bf16_t ys[32 * 512];   // 32KB [row][1024B], swizzled

    {
        const int hsel = lane >> 3;
        const int g7   = lane & 7;
        #pragma unroll
        for (int rr = 0; rr < 8; ++rr) {
            int row = w * 8 + rr;
            const char* src = (const char*)y
                + (((size_t)b * HH + hsel) * NN + nn0 + row) * 128
                + ((g7 ^ (row & 7)) * 16);
            dma16(src, (char*)ys + row * 1024);
        }
    }
    __syncthreads();

    const int rows16 = (w >> 1) * 16;
    const int mb     = dh * 2 + (w & 1);
    const char* yrow = (const char*)ys + (rows16 + c) * 1024;

    f32x4 acc = (f32x4){0.f, 0.f, 0.f, 0.f};
    #pragma unroll
    for (int kk = 0; kk < 16; ++kk) {
        int g = kk * 4 + quad;
        bf16x8 bfrag = *(const bf16x8*)(yrow + (((g & ~7) | ((g & 7) ^ cq)) * 16));
        bf16x8 afrag = *(const bf16x8*)((const char*)Wut
                        + (size_t)(mb * 16 + c) * 1024 + kk * 64 + quad * 16);
        acc = MFMA(afrag, bfrag, acc, 0, 0, 0);
    }

    float4 bb = *(const float4*)(bu + mb * 16 + quad * 4);
    float4 res = { acc[0] + bb.x, acc[1] + bb.y, acc[2] + bb.z, acc[3] + bb.w };
    float* op = out + (size_t)(row0 + rows16 + c) * DD + mb * 16 + quad * 4;
    *(float4*)op = res;
}

// -------------------------------------------------------------------------
extern "C" void kernel_launch(void* const* d_in, const int* in_sizes, int n_in,
                              void* d_out, int out_size, void* d_ws, size_t ws_size,
                              hipStream_t stream) {
    const float* x  = (const float*)d_in[0];
    const float* Wq = (const float*)d_in[1];
    const float* Wk = (const float*)d_in[2];
    const float* Wv = (const float*)d_in[3];
    const float* Wu = (const float*)d_in[4];
    const float* bu = (const float*)d_in[5];
    float* out = (float*)d_out;

    // workspace: q8 4M | k8 4M | vt 8M (f16) | y 8M (bf16) | weights 64K x4
    const size_t SEG8 = (size_t)BB * HH * NN * 64;   // 4 MiB (fp8 rows)
    const size_t SEG  = SEG8 * 2;                    // 8 MiB
    char* ws = (char*)d_ws;
    char*   q8  = ws;
    char*   k8  = ws + SEG8;
    f16_t*  vt  = (f16_t*)(ws + 2 * SEG8);
    bf16_t* y   = (bf16_t*)(ws + 2 * SEG8 + SEG);
    bf16_t* Wqt = (bf16_t*)(ws + 2 * SEG8 + 2 * SEG);
    bf16_t* Wkt = (bf16_t*)(ws + 2 * SEG8 + 2 * SEG + (1 << 16));
    bf16_t* Wvt = (bf16_t*)(ws + 2 * SEG8 + 2 * SEG + 2 * (1 << 16));
    bf16_t* Wut = (bf16_t*)(ws + 2 * SEG8 + 2 * SEG + 3 * (1 << 16));

    prep<<<dim3(16), dim3(256), 0, stream>>>(Wq, Wk, Wv, Wu, Wqt, Wkt, Wvt, Wut);
    qkv_mfma<<<dim3(128, 8), dim3(256), 0, stream>>>(x, Wqt, Wkt, Wvt, q8, k8, vt);
    flash_attn<<<dim3(HH, NN / 64, BB), dim3(256), 0, stream>>>(q8, k8, vt, y);
    out_proj<<<dim3(512), dim3(256), 0, stream>>>(y, Wut, bu, out);
}

// Round 5
// 128.096 us; speedup vs baseline: 1.1065x; 1.1065x over previous
//
#include <hip/hip_runtime.h>
#include <hip/hip_bf16.h>

// Problem constants
#define BB 4
#define NN 2048
#define DD 64
#define HH 8
#define DHH 512  // D*H

typedef __bf16 bf16_t;
typedef __bf16 bf16x8 __attribute__((ext_vector_type(8)));
typedef __bf16 bf16x4 __attribute__((ext_vector_type(4)));
typedef float f32x4 __attribute__((ext_vector_type(4)));
typedef long long i64;
typedef i64 i64x2 __attribute__((ext_vector_type(2)));
typedef _Float16 f16_t;
typedef _Float16 f16x4 __attribute__((ext_vector_type(4)));
typedef __fp16 h16x2 __attribute__((ext_vector_type(2)));   // cvt_pkrtz native type

// Async global->LDS, 16B per lane. HW places lane i at (wave-uniform base) + i*16.
__device__ __forceinline__ void dma16(const void* g, void* l) {
    __builtin_amdgcn_global_load_lds(
        (const __attribute__((address_space(1))) unsigned int*)g,
        (__attribute__((address_space(3))) unsigned int*)l,
        16, 0, 0);
}

#define MFMA   __builtin_amdgcn_mfma_f32_16x16x32_bf16
#define MFMA8  __builtin_amdgcn_mfma_f32_16x16x32_fp8_fp8
#define MFMA16F __builtin_amdgcn_mfma_f32_16x16x16f16

// q-scale 1/sqrt(64) with log2(e) folded in (softmax via exp2)
#define QSCALE 0.18033688011112042f

// fp8 q/k row layout (64 bytes per (b,h,n)): logical element d lives at byte
//   phys(d) = (d&7) + (d>>5)*8 + (((d>>3)&3) ^ swz2(n))*16,  swz2(n) = (n&3)^((n>>2)&3)
// One b128 read at granule (quad ^ swz2(n)) yields BOTH K=32 fp8 MFMA frags
// (i64x2: .x = k-lo, .y = k-hi). Widened swz2 -> flash's K ds_read_b128 hits
// all 32 banks once per 8-lane phase (conflict-free; old ^(n&3) was 2-way).
//
// vt layout (R5): [b, h, kb=n>>4, q2=(n>>2)&3, d, n&3] f16 — wave w's per-tile
// V slice (its own 16-key block, 2KB) is CONTIGUOUS in global -> wave-private
// dma16 staging; flash's V ds_read_b64 at quad*512 + db*128 + c*8 is
// conflict-free (16 distinct bank-pairs per 16-lane phase).

// -------------------------------------------------------------------------
// Kernel P: prep (unchanged). Wqt/Wkt/Wvt [512][64] bf16 (QSCALE in Wqt),
// Wut [64][512] bf16. 16 blocks.
// -------------------------------------------------------------------------
__global__ __launch_bounds__(256) void prep(
    const float* __restrict__ Wq, const float* __restrict__ Wk,
    const float* __restrict__ Wv, const float* __restrict__ Wu,
    bf16_t* __restrict__ Wqt, bf16_t* __restrict__ Wkt,
    bf16_t* __restrict__ Wvt, bf16_t* __restrict__ Wut)
{
    const int bid = blockIdx.x, tid = threadIdx.x;
    if (bid < 12) {
        const int m = bid >> 2, slice = bid & 3;
        const float* src = (m == 0) ? Wq : (m == 1) ? Wk : Wv;
        bf16_t* dst = (m == 0) ? Wqt : (m == 1) ? Wkt : Wvt;
        const float scale = (m == 0) ? QSCALE : 1.0f;
        const int dc = slice * 128 + (tid >> 1);
        const int kbase = (tid & 1) * 32;
        #pragma unroll
        for (int k0 = 0; k0 < 4; ++k0) {
            bf16x8 p;
            #pragma unroll
            for (int j = 0; j < 8; ++j)
                p[j] = (bf16_t)(src[(size_t)(kbase + k0 * 8 + j) * 512 + dc] * scale);
            *(bf16x8*)(dst + dc * 64 + kbase + k0 * 8) = p;
        }
    } else {
        const int kq = (bid - 12) * 128;
        const int dc = tid >> 2, sub = (tid & 3) * 32;
        #pragma unroll
        for (int k0 = 0; k0 < 4; ++k0) {
            bf16x8 p;
            #pragma unroll
            for (int j = 0; j < 8; ++j)
                p[j] = (bf16_t)Wu[(size_t)(kq + sub + k0 * 8 + j) * 64 + dc];
            *(bf16x8*)(Wut + dc * 512 + kq + sub + k0 * 8) = p;
        }
    }
}

// -------------------------------------------------------------------------
// Kernel A: QKV via MFMA. q,k -> fp8 e4m3 packed (widened swz2);
// vt -> f16 [b,h,kb,q2,d,klow] (R5 within-block re-index only).
// -------------------------------------------------------------------------
__global__ __launch_bounds__(256) void qkv_mfma(
    const float* __restrict__ x, const bf16_t* __restrict__ Wqt,
    const bf16_t* __restrict__ Wkt, const bf16_t* __restrict__ Wvt,
    char* __restrict__ q8, char* __restrict__ k8, f16_t* __restrict__ vt)
{
    const int n0   = blockIdx.x * 64;
    const int h    = blockIdx.y;
    const int tid  = threadIdx.x;
    const int w    = tid >> 6;
    const int lane = tid & 63;
    const int quad = lane >> 4;
    const int c    = lane & 15;
    const int cq   = c & 7;
    const int l8   = lane >> 3;
    const int lg   = (lane & 7) ^ l8;
    const int lo   = l8 * 128 + lg * 16;
    const int sw0  = ((quad    ) ^ cq) * 16;
    const int sw1  = ((quad + 4) ^ cq) * 16;
    const int w2048 = w * 2048;

    __shared__ __align__(16) float  xs[64 * 64];   // 16KB [row][256B], swizzled
    __shared__ __align__(16) bf16_t Wqs[64 * 64], Wks[64 * 64], Wvs[64 * 64];

    {
        const int rloc = lane >> 4;
        const int s    = lane & 15;
        #pragma unroll
        for (int j = 0; j < 4; ++j) {
            int chunk = w * 4 + j;
            int r7 = (chunk * 4 + rloc) & 7;
            const char* src = (const char*)(x + (size_t)(n0 + chunk * 4 + rloc) * 64)
                            + ((s & 8) | ((s & 7) ^ r7)) * 16;
            dma16(src, (char*)xs + chunk * 1024);
        }
    }
    const char* qg = (const char*)Wqt + (size_t)h * 8192;
    const char* kg = (const char*)Wkt + (size_t)h * 8192;
    const char* vg = (const char*)Wvt + (size_t)h * 8192;
    dma16(qg + w2048 + lo,        (char*)Wqs + w2048);
    dma16(qg + w2048 + 1024 + lo, (char*)Wqs + w2048 + 1024);
    dma16(kg + w2048 + lo,        (char*)Wks + w2048);
    dma16(kg + w2048 + 1024 + lo, (char*)Wks + w2048 + 1024);
    dma16(vg + w2048 + lo,        (char*)Wvs + w2048);
    dma16(vg + w2048 + 1024 + lo, (char*)Wvs + w2048 + 1024);
    __syncthreads();

    auto xfrag = [&](int row, int kk) -> bf16x8 {
        const char* rbase = (const char*)xs + row * 256;
        int g0 = kk * 8 + ((quad * 2    ) ^ cq);
        int g1 = kk * 8 + ((quad * 2 + 1) ^ cq);
        f32x4 a = *(const f32x4*)(rbase + g0 * 16);
        f32x4 b = *(const f32x4*)(rbase + g1 * 16);
        bf16x8 r;
        r[0] = (bf16_t)a[0]; r[1] = (bf16_t)a[1]; r[2] = (bf16_t)a[2]; r[3] = (bf16_t)a[3];
        r[4] = (bf16_t)b[0]; r[5] = (bf16_t)b[1]; r[6] = (bf16_t)b[2]; r[7] = (bf16_t)b[3];
        return r;
    };

    bf16x8 xf0 = xfrag(w * 16 + c, 0);
    bf16x8 xf1 = xfrag(w * 16 + c, 1);

    const int gr = n0 + w * 16 + c;
    const int bb = gr >> 11, nn = gr & 2047;
    char* qrow_g = q8 + (((size_t)bb * HH + h) * NN + nn) * 64;
    char* krow_g = k8 + (((size_t)bb * HH + h) * NN + nn) * 64;
    const int nsw = (nn & 3) ^ ((nn >> 2) & 3);   // widened granule swizzle

    #pragma unroll
    for (int mb = 0; mb < 4; ++mb) {
        const char* aq = (const char*)Wqs + (mb * 16 + c) * 128;
        const char* ak = (const char*)Wks + (mb * 16 + c) * 128;
        f32x4 accq = (f32x4){0.f, 0.f, 0.f, 0.f};
        f32x4 acck = (f32x4){0.f, 0.f, 0.f, 0.f};
        accq = MFMA(*(const bf16x8*)(aq + sw0), xf0, accq, 0, 0, 0);
        accq = MFMA(*(const bf16x8*)(aq + sw1), xf1, accq, 0, 0, 0);
        acck = MFMA(*(const bf16x8*)(ak + sw0), xf0, acck, 0, 0, 0);
        acck = MFMA(*(const bf16x8*)(ak + sw1), xf1, acck, 0, 0, 0);
        int g2  = (mb * 2 + (quad >> 1)) & 3;
        int off = ((quad & 1) * 4) + ((mb >> 1) * 8) + ((g2 ^ nsw) * 16);
        int pq = __builtin_amdgcn_cvt_pk_fp8_f32(accq[0], accq[1], 0, false);
        pq     = __builtin_amdgcn_cvt_pk_fp8_f32(accq[2], accq[3], pq, true);
        int pk = __builtin_amdgcn_cvt_pk_fp8_f32(acck[0], acck[1], 0, false);
        pk     = __builtin_amdgcn_cvt_pk_fp8_f32(acck[2], acck[3], pk, true);
        *(int*)(qrow_g + off) = pq;
        *(int*)(krow_g + off) = pk;
    }

    const char* wvrow = (const char*)Wvs + (w * 16 + c) * 128;
    bf16x8 vf0 = *(const bf16x8*)(wvrow + sw0);
    bf16x8 vf1 = *(const bf16x8*)(wvrow + sw1);

    const int bb2 = n0 >> 11;
    // vt [b,h,kb,q2,d,klow]: lane (quad,c) acc j = V^T[d=w*16+c][k=nb*16+quad*4+j]
    // -> f16 offset kb*1024 + quad*256 + d*4 + j  (kb = (n0&2047)>>4 + nb)
    f16_t* vtb = vt + ((size_t)bb2 * HH + h) * (size_t)(DD * NN)
               + (size_t)((n0 & 2047) >> 4) * 1024 + quad * 256 + (w * 16 + c) * 4;

    #pragma unroll
    for (int nb = 0; nb < 4; ++nb) {
        f32x4 acc = (f32x4){0.f, 0.f, 0.f, 0.f};
        acc = MFMA(xfrag(nb * 16 + c, 0), vf0, acc, 0, 0, 0);
        acc = MFMA(xfrag(nb * 16 + c, 1), vf1, acc, 0, 0, 0);
        f16x4 p = { (f16_t)acc[0], (f16_t)acc[1], (f16_t)acc[2], (f16_t)acc[3] };
        *(f16x4*)(vtb + nb * 1024) = p;
    }
}

// -------------------------------------------------------------------------
// Kernel B: flash attention — R5: back to the PROVEN R0 structure
// (global_load_lds double-buffer, one __syncthreads per phase, drain at
// barrier) with (a) fully wave-private staging (K rows w*16..+15; V = own
// contiguous 2KB key-block), (b) conflict-free LDS reads (widened K swz;
// [q2][d][klow] V layout), (c) 2 tiles per phase -> 16 barriers not 32.
// LDS: 2 buffers x 24KB (K 8K + V 16K). Epilogue overlay as before.
// -------------------------------------------------------------------------
__global__ __launch_bounds__(256, 3) void flash_attn(
    const char* __restrict__ q8, const char* __restrict__ k8,
    const f16_t* __restrict__ vt, bf16_t* __restrict__ y)
{
    const int h    = blockIdx.x;          // head first -> XCD L2 locality
    const int n0   = blockIdx.y * 64;
    const int b    = blockIdx.z;
    const int tid  = threadIdx.x;
    const int w    = tid >> 6;
    const int lane = tid & 63;
    const int quad = lane >> 4;
    const int c    = lane & 15;
    const int ksw  = (quad ^ (c & 3) ^ ((c >> 2) & 3)) * 16;  // widened fp8 swz

    __shared__ __align__(16) char SM[49152];   // 2 x 24KB; epilogue overlay 17KB

    const size_t bh = (size_t)(b * HH + h);
    const char* qp = q8 + bh * (size_t)(NN * 64);
    const char* kp = k8 + bh * (size_t)(NN * 64);
    const char* vp = (const char*)(vt + bh * (size_t)(DD * NN));

    // Q B-frags (fp8 packed)
    i64x2 qf[4];
    #pragma unroll
    for (int cb = 0; cb < 4; ++cb)
        qf[cb] = *(const i64x2*)(qp + (size_t)(n0 + cb * 16 + c) * 64 + ksw);

    // DMA source lane pointers (wave-private contiguous slices)
    const char* kdma = kp + w * 1024 + lane * 16;   // + tile*4096 (1KB: rows w*16..+15)
    const char* vdma = vp + w * 2048 + lane * 16;   // + tile*8192 (2KB: key-block t*4+w)

    // LDS read offsets (within 24KB buffer): K [0,8K) w*2048+hf*1024;
    // V [8K,24K) w*4096+hf*2048, frag db at quad*512 + db*128 + c*8.
    const int kro = w * 2048 + c * 64 + ksw;
    const int vro = 8192 + w * 4096 + quad * 512 + c * 8;

    f32x4 lsum4[4];
    f32x4 o[4][4];   // o[db][cb]: O^T[d=db*16+quad*4+r][q=cb*16+c]
    #pragma unroll
    for (int cb = 0; cb < 4; ++cb) lsum4[cb] = (f32x4){0.f, 0.f, 0.f, 0.f};
    #pragma unroll
    for (int db = 0; db < 4; ++db)
        #pragma unroll
        for (int cb = 0; cb < 4; ++cb) o[db][cb] = (f32x4){0.f, 0.f, 0.f, 0.f};

    // Stage phase p (tiles 2p, 2p+1) into buffer buf: 6 dma16 per wave.
    #define STAGE2(p, buf) do {                                               \
        char* B_ = SM + (buf) * 24576;                                        \
        const size_t t0_ = (size_t)(2 * (p));                                 \
        dma16(kdma + t0_ * 4096,         B_ + w * 2048);                      \
        dma16(kdma + t0_ * 4096 + 4096,  B_ + w * 2048 + 1024);               \
        dma16(vdma + t0_ * 8192,         B_ + 8192 + w * 4096);               \
        dma16(vdma + t0_ * 8192 + 1024,  B_ + 8192 + w * 4096 + 1024);        \
        dma16(vdma + t0_ * 8192 + 8192,  B_ + 8192 + w * 4096 + 2048);        \
        dma16(vdma + t0_ * 8192 + 9216,  B_ + 8192 + w * 4096 + 3072);        \
    } while (0)

    // Compute one tile (half hf of buffer buf).
    #define BODY2(buf, hf) do {                                               \
        const char* kb_b = SM + (buf) * 24576;                                \
        i64x2 kf_ = *(const i64x2*)(kb_b + kro + (hf) * 1024);                \
        f16x4 vf_[4];                                                         \
        _Pragma("unroll")                                                     \
        for (int db = 0; db < 4; ++db)                                        \
            vf_[db] = *(const f16x4*)(kb_b + vro + (hf) * 2048 + db * 128);   \
        _Pragma("unroll")                                                     \
        for (int cb = 0; cb < 4; ++cb) {                                      \
            f32x4 s_ = (f32x4){0.f, 0.f, 0.f, 0.f};                           \
            s_ = MFMA8(kf_.x, qf[cb].x, s_, 0, 0, 0);                         \
            s_ = MFMA8(kf_.y, qf[cb].y, s_, 0, 0, 0);                         \
            float p0_ = __builtin_amdgcn_exp2f(s_[0]);                        \
            float p1_ = __builtin_amdgcn_exp2f(s_[1]);                        \
            float p2_ = __builtin_amdgcn_exp2f(s_[2]);                        \
            float p3_ = __builtin_amdgcn_exp2f(s_[3]);                        \
            lsum4[cb] += (f32x4){p0_, p1_, p2_, p3_};                         \
            h16x2 ab_ = __builtin_amdgcn_cvt_pkrtz(p0_, p1_);                 \
            h16x2 cd_ = __builtin_amdgcn_cvt_pkrtz(p2_, p3_);                 \
            f16x4 pf_;                                                        \
            __builtin_memcpy(&pf_, &ab_, 4);                                  \
            __builtin_memcpy((char*)&pf_ + 4, &cd_, 4);                       \
            _Pragma("unroll")                                                 \
            for (int db = 0; db < 4; ++db)                                    \
                o[db][cb] = MFMA16F(vf_[db], pf_, o[db][cb], 0, 0, 0);        \
        }                                                                     \
    } while (0)

    // Prologue (R0 pattern): stage phase 0, drain, stage phase 1.
    STAGE2(0, 0);
    __syncthreads();
    STAGE2(1, 1);

    #pragma unroll 1
    for (int p = 0; p < 16; ++p) {
        if (p > 0) {
            __syncthreads();                 // drains STAGE2(p)'s dma16s
            if (p < 15) STAGE2(p + 1, (p + 1) & 1);
        }
        BODY2(p & 1, 0);
        BODY2(p & 1, 1);
    }

    #undef STAGE2
    #undef BODY2

    // horizontal lsum
    float lsum[4];
    #pragma unroll
    for (int cb = 0; cb < 4; ++cb)
        lsum[cb] = (lsum4[cb][0] + lsum4[cb][1]) + (lsum4[cb][2] + lsum4[cb][3]);

    __syncthreads();   // all phase-15 LDS reads done before overlay reuse

    // ---- epilogue: cross-wave reduction (Ob = SM[0..16K), Lb = SM+16K) ----
    char*  Ob = SM;
    float* Lb = (float*)(SM + 16384);

    #pragma unroll
    for (int cb = 0; cb < 4; ++cb) {
        lsum[cb] += __shfl_xor(lsum[cb], 16, 64);
        lsum[cb] += __shfl_xor(lsum[cb], 32, 64);
    }
    if (quad == 0) {
        #pragma unroll
        for (int cb = 0; cb < 4; ++cb)
            Lb[(w * 4 + cb) * 16 + c] = lsum[cb];
    }

    // O: sequential accumulate across waves
    #pragma unroll
    for (int ww = 0; ww < 4; ++ww) {
        if (w == ww) {
            #pragma unroll
            for (int db = 0; db < 4; ++db) {
                #pragma unroll
                for (int cb = 0; cb < 4; ++cb) {
                    char* p = Ob + (size_t)(((db * 4 + cb) * 4 + quad) * 16 + c) * 16;
                    f32x4 v = o[db][cb];
                    if (ww > 0) v += *(const f32x4*)p;
                    *(f32x4*)p = v;
                }
            }
        }
        __syncthreads();
    }

    // readout: thread t -> q-row n_loc = t&63, d-quarter dq = t>>6
    {
        const int n_loc = tid & 63;
        const int dq    = tid >> 6;
        const int qcb   = n_loc >> 4;
        const int cc    = n_loc & 15;
        float l = Lb[(0 * 4 + qcb) * 16 + cc] + Lb[(1 * 4 + qcb) * 16 + cc]
                + Lb[(2 * 4 + qcb) * 16 + cc] + Lb[(3 * 4 + qcb) * 16 + cc];
        float inv = 1.0f / l;
        float vals[16];
        #pragma unroll
        for (int q2 = 0; q2 < 4; ++q2) {
            f32x4 v = *(const f32x4*)(Ob
                    + (size_t)(((dq * 4 + qcb) * 4 + q2) * 16 + cc) * 16);
            vals[q2 * 4 + 0] = v[0]; vals[q2 * 4 + 1] = v[1];
            vals[q2 * 4 + 2] = v[2]; vals[q2 * 4 + 3] = v[3];
        }
        bf16x8 o0, o1;
        #pragma unroll
        for (int j = 0; j < 8; ++j) {
            o0[j] = (bf16_t)(vals[j] * inv);
            o1[j] = (bf16_t)(vals[8 + j] * inv);
        }
        bf16_t* yrow = y + bh * (size_t)(NN * DD) + (size_t)(n0 + n_loc) * DD + dq * 16;
        *(bf16x8*)(yrow)     = o0;
        *(bf16x8*)(yrow + 8) = o1;
    }
}

// -------------------------------------------------------------------------
// Kernel C: output projection via MFMA (unchanged). 512 blocks.
// -------------------------------------------------------------------------
__global__ __launch_bounds__(256) void out_proj(
    const bf16_t* __restrict__ y,    // [b,h,n,d] bf16
    const bf16_t* __restrict__ Wut,  // [64][512]
    const float* __restrict__ bu, float* __restrict__ out)
{
    const int rt   = blockIdx.x >> 1;
    const int dh   = blockIdx.x & 1;
    const int row0 = rt * 32;
    const int b    = row0 >> 11;
    const int nn0  = row0 & 2047;
    const int tid  = threadIdx.x;
    const int w    = tid >> 6;
    const int lane = tid & 63;
    const int quad = lane >> 4;
    const int c    = lane & 15;
    const int cq   = c & 7;

    __shared__ __align__(16) bf16_t ys[32 * 512];   // 32KB [row][1024B], swizzled

    {
        const int hsel = lane >> 3;
        const int g7   = lane & 7;
        #pragma unroll
        for (int rr = 0; rr < 8; ++rr) {
            int row = w * 8 + rr;
            const char* src = (const char*)y
                + (((size_t)b * HH + hsel) * NN + nn0 + row) * 128
                + ((g7 ^ (row & 7)) * 16);
            dma16(src, (char*)ys + row * 1024);
        }
    }
    __syncthreads();

    const int rows16 = (w >> 1) * 16;
    const int mb     = dh * 2 + (w & 1);
    const char* yrow = (const char*)ys + (rows16 + c) * 1024;

    f32x4 acc = (f32x4){0.f, 0.f, 0.f, 0.f};
    #pragma unroll
    for (int kk = 0; kk < 16; ++kk) {
        int g = kk * 4 + quad;
        bf16x8 bfrag = *(const bf16x8*)(yrow + (((g & ~7) | ((g & 7) ^ cq)) * 16));
        bf16x8 afrag = *(const bf16x8*)((const char*)Wut
                        + (size_t)(mb * 16 + c) * 1024 + kk * 64 + quad * 16);
        acc = MFMA(afrag, bfrag, acc, 0, 0, 0);
    }

    float4 bb = *(const float4*)(bu + mb * 16 + quad * 4);
    float4 res = { acc[0] + bb.x, acc[1] + bb.y, acc[2] + bb.z, acc[3] + bb.w };
    float* op = out + (size_t)(row0 + rows16 + c) * DD + mb * 16 + quad * 4;
    *(float4*)op = res;
}

// -------------------------------------------------------------------------
extern "C" void kernel_launch(void* const* d_in, const int* in_sizes, int n_in,
                              void* d_out, int out_size, void* d_ws, size_t ws_size,
                              hipStream_t stream) {
    const float* x  = (const float*)d_in[0];
    const float* Wq = (const float*)d_in[1];
    const float* Wk = (const float*)d_in[2];
    const float* Wv = (const float*)d_in[3];
    const float* Wu = (const float*)d_in[4];
    const float* bu = (const float*)d_in[5];
    float* out = (float*)d_out;

    // workspace: q8 4M | k8 4M | vt 8M (f16) | y 8M (bf16) | weights 64K x4
    const size_t SEG8 = (size_t)BB * HH * NN * 64;   // 4 MiB (fp8 rows)
    const size_t SEG  = SEG8 * 2;                    // 8 MiB
    char* ws = (char*)d_ws;
    char*   q8  = ws;
    char*   k8  = ws + SEG8;
    f16_t*  vt  = (f16_t*)(ws + 2 * SEG8);
    bf16_t* y   = (bf16_t*)(ws + 2 * SEG8 + SEG);
    bf16_t* Wqt = (bf16_t*)(ws + 2 * SEG8 + 2 * SEG);
    bf16_t* Wkt = (bf16_t*)(ws + 2 * SEG8 + 2 * SEG + (1 << 16));
    bf16_t* Wvt = (bf16_t*)(ws + 2 * SEG8 + 2 * SEG + 2 * (1 << 16));
    bf16_t* Wut = (bf16_t*)(ws + 2 * SEG8 + 2 * SEG + 3 * (1 << 16));

    prep<<<dim3(16), dim3(256), 0, stream>>>(Wq, Wk, Wv, Wu, Wqt, Wkt, Wvt, Wut);
    qkv_mfma<<<dim3(128, 8), dim3(256), 0, stream>>>(x, Wqt, Wkt, Wvt, q8, k8, vt);
    flash_attn<<<dim3(HH, NN / 64, BB), dim3(256), 0, stream>>>(q8, k8, vt, y);
    out_proj<<<dim3(512), dim3(256), 0, stream>>>(y, Wut, bu, out);
}

// Round 6
// 128.007 us; speedup vs baseline: 1.1073x; 1.0007x over previous
//
#include <hip/hip_runtime.h>
#include <hip/hip_bf16.h>

// Problem constants
#define BB 4
#define NN 2048
#define DD 64
#define HH 8
#define DHH 512  // D*H

typedef __bf16 bf16_t;
typedef __bf16 bf16x8 __attribute__((ext_vector_type(8)));
typedef __bf16 bf16x4 __attribute__((ext_vector_type(4)));
typedef float f32x4 __attribute__((ext_vector_type(4)));
typedef long long i64;
typedef i64 i64x2 __attribute__((ext_vector_type(2)));
typedef _Float16 f16_t;
typedef _Float16 f16x4 __attribute__((ext_vector_type(4)));
typedef __fp16 h16x2 __attribute__((ext_vector_type(2)));   // cvt_pkrtz native type

// Async global->LDS, 16B per lane. HW places lane i at (wave-uniform base) + i*16.
__device__ __forceinline__ void dma16(const void* g, void* l) {
    __builtin_amdgcn_global_load_lds(
        (const __attribute__((address_space(1))) unsigned int*)g,
        (__attribute__((address_space(3))) unsigned int*)l,
        16, 0, 0);
}

#define MFMA   __builtin_amdgcn_mfma_f32_16x16x32_bf16
#define MFMA8  __builtin_amdgcn_mfma_f32_16x16x32_fp8_fp8
#define MFMA16F __builtin_amdgcn_mfma_f32_16x16x16f16

// q-scale 1/sqrt(64) with log2(e) folded in (softmax via exp2)
#define QSCALE 0.18033688011112042f

// fp8 q/k row layout (64 bytes per (b,h,n)): logical element d lives at byte
//   phys(d) = (d&7) + (d>>5)*8 + (((d>>3)&3) ^ swz2(n))*16,  swz2(n) = (n&3)^((n>>2)&3)
// One b128 read at granule (quad ^ swz2(n)) yields BOTH K=32 fp8 MFMA frags
// (i64x2: .x = k-lo, .y = k-hi). Widened swz2 -> K ds_read_b128 conflict-free.
//
// vt layout: [b, h, kb=n>>4, q2=(n>>2)&3, d, n&3] f16 — each 16-key block is
// a contiguous 2KB slice; V ds_read_b64 at quad*512 + db*128 + c*8 is
// conflict-free.
//
// R6 flash geometry: 8 waves (512 thr), Q-tile 128. wave = (wq=q-half, wk=
// key-quad). Staged K/V shared by both q-halves -> per-q staging + barrier
// cost halves; 512 blocks = exactly 2/CU; 16 waves/CU.

// -------------------------------------------------------------------------
// Kernel P: prep (unchanged). Wqt/Wkt/Wvt [512][64] bf16 (QSCALE in Wqt),
// Wut [64][512] bf16. 16 blocks.
// -------------------------------------------------------------------------
__global__ __launch_bounds__(256) void prep(
    const float* __restrict__ Wq, const float* __restrict__ Wk,
    const float* __restrict__ Wv, const float* __restrict__ Wu,
    bf16_t* __restrict__ Wqt, bf16_t* __restrict__ Wkt,
    bf16_t* __restrict__ Wvt, bf16_t* __restrict__ Wut)
{
    const int bid = blockIdx.x, tid = threadIdx.x;
    if (bid < 12) {
        const int m = bid >> 2, slice = bid & 3;
        const float* src = (m == 0) ? Wq : (m == 1) ? Wk : Wv;
        bf16_t* dst = (m == 0) ? Wqt : (m == 1) ? Wkt : Wvt;
        const float scale = (m == 0) ? QSCALE : 1.0f;
        const int dc = slice * 128 + (tid >> 1);
        const int kbase = (tid & 1) * 32;
        #pragma unroll
        for (int k0 = 0; k0 < 4; ++k0) {
            bf16x8 p;
            #pragma unroll
            for (int j = 0; j < 8; ++j)
                p[j] = (bf16_t)(src[(size_t)(kbase + k0 * 8 + j) * 512 + dc] * scale);
            *(bf16x8*)(dst + dc * 64 + kbase + k0 * 8) = p;
        }
    } else {
        const int kq = (bid - 12) * 128;
        const int dc = tid >> 2, sub = (tid & 3) * 32;
        #pragma unroll
        for (int k0 = 0; k0 < 4; ++k0) {
            bf16x8 p;
            #pragma unroll
            for (int j = 0; j < 8; ++j)
                p[j] = (bf16_t)Wu[(size_t)(kq + sub + k0 * 8 + j) * 64 + dc];
            *(bf16x8*)(Wut + dc * 512 + kq + sub + k0 * 8) = p;
        }
    }
}

// -------------------------------------------------------------------------
// Kernel A: QKV via MFMA (unchanged from R5 — verified). q,k -> fp8 e4m3
// packed (widened swz2); vt -> f16 [b,h,kb,q2,d,klow].
// -------------------------------------------------------------------------
__global__ __launch_bounds__(256) void qkv_mfma(
    const float* __restrict__ x, const bf16_t* __restrict__ Wqt,
    const bf16_t* __restrict__ Wkt, const bf16_t* __restrict__ Wvt,
    char* __restrict__ q8, char* __restrict__ k8, f16_t* __restrict__ vt)
{
    const int n0   = blockIdx.x * 64;
    const int h    = blockIdx.y;
    const int tid  = threadIdx.x;
    const int w    = tid >> 6;
    const int lane = tid & 63;
    const int quad = lane >> 4;
    const int c    = lane & 15;
    const int cq   = c & 7;
    const int l8   = lane >> 3;
    const int lg   = (lane & 7) ^ l8;
    const int lo   = l8 * 128 + lg * 16;
    const int sw0  = ((quad    ) ^ cq) * 16;
    const int sw1  = ((quad + 4) ^ cq) * 16;
    const int w2048 = w * 2048;

    __shared__ __align__(16) float  xs[64 * 64];   // 16KB [row][256B], swizzled
    __shared__ __align__(16) bf16_t Wqs[64 * 64], Wks[64 * 64], Wvs[64 * 64];

    {
        const int rloc = lane >> 4;
        const int s    = lane & 15;
        #pragma unroll
        for (int j = 0; j < 4; ++j) {
            int chunk = w * 4 + j;
            int r7 = (chunk * 4 + rloc) & 7;
            const char* src = (const char*)(x + (size_t)(n0 + chunk * 4 + rloc) * 64)
                            + ((s & 8) | ((s & 7) ^ r7)) * 16;
            dma16(src, (char*)xs + chunk * 1024);
        }
    }
    const char* qg = (const char*)Wqt + (size_t)h * 8192;
    const char* kg = (const char*)Wkt + (size_t)h * 8192;
    const char* vg = (const char*)Wvt + (size_t)h * 8192;
    dma16(qg + w2048 + lo,        (char*)Wqs + w2048);
    dma16(qg + w2048 + 1024 + lo, (char*)Wqs + w2048 + 1024);
    dma16(kg + w2048 + lo,        (char*)Wks + w2048);
    dma16(kg + w2048 + 1024 + lo, (char*)Wks + w2048 + 1024);
    dma16(vg + w2048 + lo,        (char*)Wvs + w2048);
    dma16(vg + w2048 + 1024 + lo, (char*)Wvs + w2048 + 1024);
    __syncthreads();

    auto xfrag = [&](int row, int kk) -> bf16x8 {
        const char* rbase = (const char*)xs + row * 256;
        int g0 = kk * 8 + ((quad * 2    ) ^ cq);
        int g1 = kk * 8 + ((quad * 2 + 1) ^ cq);
        f32x4 a = *(const f32x4*)(rbase + g0 * 16);
        f32x4 b = *(const f32x4*)(rbase + g1 * 16);
        bf16x8 r;
        r[0] = (bf16_t)a[0]; r[1] = (bf16_t)a[1]; r[2] = (bf16_t)a[2]; r[3] = (bf16_t)a[3];
        r[4] = (bf16_t)b[0]; r[5] = (bf16_t)b[1]; r[6] = (bf16_t)b[2]; r[7] = (bf16_t)b[3];
        return r;
    };

    bf16x8 xf0 = xfrag(w * 16 + c, 0);
    bf16x8 xf1 = xfrag(w * 16 + c, 1);

    const int gr = n0 + w * 16 + c;
    const int bb = gr >> 11, nn = gr & 2047;
    char* qrow_g = q8 + (((size_t)bb * HH + h) * NN + nn) * 64;
    char* krow_g = k8 + (((size_t)bb * HH + h) * NN + nn) * 64;
    const int nsw = (nn & 3) ^ ((nn >> 2) & 3);   // widened granule swizzle

    #pragma unroll
    for (int mb = 0; mb < 4; ++mb) {
        const char* aq = (const char*)Wqs + (mb * 16 + c) * 128;
        const char* ak = (const char*)Wks + (mb * 16 + c) * 128;
        f32x4 accq = (f32x4){0.f, 0.f, 0.f, 0.f};
        f32x4 acck = (f32x4){0.f, 0.f, 0.f, 0.f};
        accq = MFMA(*(const bf16x8*)(aq + sw0), xf0, accq, 0, 0, 0);
        accq = MFMA(*(const bf16x8*)(aq + sw1), xf1, accq, 0, 0, 0);
        acck = MFMA(*(const bf16x8*)(ak + sw0), xf0, acck, 0, 0, 0);
        acck = MFMA(*(const bf16x8*)(ak + sw1), xf1, acck, 0, 0, 0);
        int g2  = (mb * 2 + (quad >> 1)) & 3;
        int off = ((quad & 1) * 4) + ((mb >> 1) * 8) + ((g2 ^ nsw) * 16);
        int pq = __builtin_amdgcn_cvt_pk_fp8_f32(accq[0], accq[1], 0, false);
        pq     = __builtin_amdgcn_cvt_pk_fp8_f32(accq[2], accq[3], pq, true);
        int pk = __builtin_amdgcn_cvt_pk_fp8_f32(acck[0], acck[1], 0, false);
        pk     = __builtin_amdgcn_cvt_pk_fp8_f32(acck[2], acck[3], pk, true);
        *(int*)(qrow_g + off) = pq;
        *(int*)(krow_g + off) = pk;
    }

    const char* wvrow = (const char*)Wvs + (w * 16 + c) * 128;
    bf16x8 vf0 = *(const bf16x8*)(wvrow + sw0);
    bf16x8 vf1 = *(const bf16x8*)(wvrow + sw1);

    const int bb2 = n0 >> 11;
    // vt [b,h,kb,q2,d,klow]: lane (quad,c) acc j = V^T[d=w*16+c][k=nb*16+quad*4+j]
    f16_t* vtb = vt + ((size_t)bb2 * HH + h) * (size_t)(DD * NN)
               + (size_t)((n0 & 2047) >> 4) * 1024 + quad * 256 + (w * 16 + c) * 4;

    #pragma unroll
    for (int nb = 0; nb < 4; ++nb) {
        f32x4 acc = (f32x4){0.f, 0.f, 0.f, 0.f};
        acc = MFMA(xfrag(nb * 16 + c, 0), vf0, acc, 0, 0, 0);
        acc = MFMA(xfrag(nb * 16 + c, 1), vf1, acc, 0, 0, 0);
        f16x4 p = { (f16_t)acc[0], (f16_t)acc[1], (f16_t)acc[2], (f16_t)acc[3] };
        *(f16x4*)(vtb + nb * 1024) = p;
    }
}

// -------------------------------------------------------------------------
// Kernel B: flash attention — R6: 8 waves (512 thr), Q-tile 128.
// wave w = (wq = w>>2 q-half, wk = w&3 key-quad). Phase structure, body,
// swizzles, barrier/drain discipline IDENTICAL to R5 (proven); staged K/V
// shared by both q-halves. LDS 2 x 24KB; epilogue overlay 34KB.
// -------------------------------------------------------------------------
__global__ __launch_bounds__(512, 4) void flash_attn(
    const char* __restrict__ q8, const char* __restrict__ k8,
    const f16_t* __restrict__ vt, bf16_t* __restrict__ y)
{
    const int h    = blockIdx.x;          // head first -> XCD L2 locality
    const int nb0  = blockIdx.y * 128;    // q-tile base (128 rows)
    const int b    = blockIdx.z;
    const int tid  = threadIdx.x;
    const int w    = tid >> 6;
    const int wq   = w >> 2;              // q-half 0/1
    const int wk   = w & 3;               // key quad 0..3
    const int lane = tid & 63;
    const int quad = lane >> 4;
    const int c    = lane & 15;
    const int ksw  = (quad ^ (c & 3) ^ ((c >> 2) & 3)) * 16;  // widened fp8 swz

    __shared__ __align__(16) char SM[49152];   // 2 x 24KB; epilogue overlay 34KB

    const size_t bh = (size_t)(b * HH + h);
    const char* qp = q8 + bh * (size_t)(NN * 64);
    const char* kp = k8 + bh * (size_t)(NN * 64);
    const char* vp = (const char*)(vt + bh * (size_t)(DD * NN));

    // Q B-frags (fp8 packed) — this wave's q-half
    const int qbase = nb0 + wq * 64;
    i64x2 qf[4];
    #pragma unroll
    for (int cb = 0; cb < 4; ++cb)
        qf[cb] = *(const i64x2*)(qp + (size_t)(qbase + cb * 16 + c) * 64 + ksw);

    // DMA source lane pointers (key-quad-private contiguous slices)
    const char* kdma = kp + wk * 1024 + lane * 16;   // + tile*4096 (1KB: keys t*64+wk*16..+15)
    const char* vdma = vp + wk * 2048 + lane * 16;   // + tile*8192 (2KB: key-block t*4+wk)

    // LDS read offsets (within 24KB buffer): K [0,8K) wk*2048+hf*1024;
    // V [8K,24K) wk*4096+hf*2048, frag db at quad*512 + db*128 + c*8.
    const int kro = wk * 2048 + c * 64 + ksw;
    const int vro = 8192 + wk * 4096 + quad * 512 + c * 8;

    f32x4 lsum4[4];
    f32x4 o[4][4];   // o[db][cb]: O^T[d=db*16+quad*4+r][q=qbase+cb*16+c]
    #pragma unroll
    for (int cb = 0; cb < 4; ++cb) lsum4[cb] = (f32x4){0.f, 0.f, 0.f, 0.f};
    #pragma unroll
    for (int db = 0; db < 4; ++db)
        #pragma unroll
        for (int cb = 0; cb < 4; ++cb) o[db][cb] = (f32x4){0.f, 0.f, 0.f, 0.f};

    // Stage phase p (tiles 2p, 2p+1) into buffer buf: 3 dma16 per wave,
    // split across q-halves (both halves stage; K by wq=0, V split).
    #define STAGE2(p, buf) do {                                               \
        char* B_ = SM + (buf) * 24576;                                        \
        const size_t t0_ = (size_t)(2 * (p));                                 \
        if (wq == 0) {                                                        \
            dma16(kdma + t0_ * 4096,         B_ + wk * 2048);                 \
            dma16(kdma + t0_ * 4096 + 4096,  B_ + wk * 2048 + 1024);          \
            dma16(vdma + t0_ * 8192,         B_ + 8192 + wk * 4096);          \
        } else {                                                              \
            dma16(vdma + t0_ * 8192 + 1024,  B_ + 8192 + wk * 4096 + 1024);   \
            dma16(vdma + t0_ * 8192 + 8192,  B_ + 8192 + wk * 4096 + 2048);   \
            dma16(vdma + t0_ * 8192 + 9216,  B_ + 8192 + wk * 4096 + 3072);   \
        }                                                                     \
    } while (0)

    // Compute one tile (half hf of buffer buf) — identical to R5.
    #define BODY2(buf, hf) do {                                               \
        const char* kb_b = SM + (buf) * 24576;                                \
        i64x2 kf_ = *(const i64x2*)(kb_b + kro + (hf) * 1024);                \
        f16x4 vf_[4];                                                         \
        _Pragma("unroll")                                                     \
        for (int db = 0; db < 4; ++db)                                        \
            vf_[db] = *(const f16x4*)(kb_b + vro + (hf) * 2048 + db * 128);   \
        _Pragma("unroll")                                                     \
        for (int cb = 0; cb < 4; ++cb) {                                      \
            f32x4 s_ = (f32x4){0.f, 0.f, 0.f, 0.f};                           \
            s_ = MFMA8(kf_.x, qf[cb].x, s_, 0, 0, 0);                         \
            s_ = MFMA8(kf_.y, qf[cb].y, s_, 0, 0, 0);                         \
            float p0_ = __builtin_amdgcn_exp2f(s_[0]);                        \
            float p1_ = __builtin_amdgcn_exp2f(s_[1]);                        \
            float p2_ = __builtin_amdgcn_exp2f(s_[2]);                        \
            float p3_ = __builtin_amdgcn_exp2f(s_[3]);                        \
            lsum4[cb] += (f32x4){p0_, p1_, p2_, p3_};                         \
            h16x2 ab_ = __builtin_amdgcn_cvt_pkrtz(p0_, p1_);                 \
            h16x2 cd_ = __builtin_amdgcn_cvt_pkrtz(p2_, p3_);                 \
            f16x4 pf_;                                                        \
            __builtin_memcpy(&pf_, &ab_, 4);                                  \
            __builtin_memcpy((char*)&pf_ + 4, &cd_, 4);                       \
            _Pragma("unroll")                                                 \
            for (int db = 0; db < 4; ++db)                                    \
                o[db][cb] = MFMA16F(vf_[db], pf_, o[db][cb], 0, 0, 0);        \
        }                                                                     \
    } while (0)

    // Prologue (proven pattern): stage phase 0, drain, stage phase 1.
    STAGE2(0, 0);
    __syncthreads();
    STAGE2(1, 1);

    #pragma unroll 1
    for (int p = 0; p < 16; ++p) {
        if (p > 0) {
            __syncthreads();                 // drains STAGE2(p)'s dma16s
            if (p < 15) STAGE2(p + 1, (p + 1) & 1);
        }
        BODY2(p & 1, 0);
        BODY2(p & 1, 1);
    }

    #undef STAGE2
    #undef BODY2

    // horizontal lsum
    float lsum[4];
    #pragma unroll
    for (int cb = 0; cb < 4; ++cb)
        lsum[cb] = (lsum4[cb][0] + lsum4[cb][1]) + (lsum4[cb][2] + lsum4[cb][3]);

    __syncthreads();   // all phase-15 LDS reads done before overlay reuse

    // ---- epilogue: per-half reduction. Obh = SM + wq*16K (2 x 16KB),
    // Lbh = SM + 32K + wq*1K (2 x 1KB). ----
    char*  Obh = SM + wq * 16384;
    float* Lbh = (float*)(SM + 32768 + wq * 1024);

    #pragma unroll
    for (int cb = 0; cb < 4; ++cb) {
        lsum[cb] += __shfl_xor(lsum[cb], 16, 64);
        lsum[cb] += __shfl_xor(lsum[cb], 32, 64);
    }
    if (quad == 0) {
        #pragma unroll
        for (int cb = 0; cb < 4; ++cb)
            Lbh[(wk * 4 + cb) * 16 + c] = lsum[cb];
    }

    // O: sequential accumulate across the 4 key-quads (both halves in parallel)
    #pragma unroll
    for (int ww = 0; ww < 4; ++ww) {
        if (wk == ww) {
            #pragma unroll
            for (int db = 0; db < 4; ++db) {
                #pragma unroll
                for (int cb = 0; cb < 4; ++cb) {
                    char* p = Obh + (size_t)(((db * 4 + cb) * 4 + quad) * 16 + c) * 16;
                    f32x4 v = o[db][cb];
                    if (ww > 0) v += *(const f32x4*)p;
                    *(f32x4*)p = v;
                }
            }
        }
        __syncthreads();
    }

    // readout: thread t -> q-row n_loc = t&127, d-16-block dq = t>>7 (0..3)
    {
        const int n_loc = tid & 127;
        const int dq    = tid >> 7;
        const int qh    = n_loc >> 6;
        const int r64   = n_loc & 63;
        const int qcb   = r64 >> 4;
        const int cc    = r64 & 15;
        const char*  Or = SM + qh * 16384;
        const float* Lr = (const float*)(SM + 32768 + qh * 1024);
        float l = Lr[(0 * 4 + qcb) * 16 + cc] + Lr[(1 * 4 + qcb) * 16 + cc]
                + Lr[(2 * 4 + qcb) * 16 + cc] + Lr[(3 * 4 + qcb) * 16 + cc];
        float inv = 1.0f / l;
        float vals[16];
        #pragma unroll
        for (int q2 = 0; q2 < 4; ++q2) {
            f32x4 v = *(const f32x4*)(Or
                    + (size_t)(((dq * 4 + qcb) * 4 + q2) * 16 + cc) * 16);
            vals[q2 * 4 + 0] = v[0]; vals[q2 * 4 + 1] = v[1];
            vals[q2 * 4 + 2] = v[2]; vals[q2 * 4 + 3] = v[3];
        }
        bf16x8 o0, o1;
        #pragma unroll
        for (int j = 0; j < 8; ++j) {
            o0[j] = (bf16_t)(vals[j] * inv);
            o1[j] = (bf16_t)(vals[8 + j] * inv);
        }
        bf16_t* yrow = y + bh * (size_t)(NN * DD)
                     + (size_t)(nb0 + n_loc) * DD + dq * 16;
        *(bf16x8*)(yrow)     = o0;
        *(bf16x8*)(yrow + 8) = o1;
    }
}

// -------------------------------------------------------------------------
// Kernel C: output projection via MFMA (unchanged). 512 blocks.
// -------------------------------------------------------------------------
__global__ __launch_bounds__(256) void out_proj(
    const bf16_t* __restrict__ y,    // [b,h,n,d] bf16
    const bf16_t* __restrict__ Wut,  // [64][512]
    const float* __restrict__ bu, float* __restrict__ out)
{
    const int rt   = blockIdx.x >> 1;
    const int dh   = blockIdx.x & 1;
    const int row0 = rt * 32;
    const int b    = row0 >> 11;
    const int nn0  = row0 & 2047;
    const int tid  = threadIdx.x;
    const int w    = tid >> 6;
    const int lane = tid & 63;
    const int quad = lane >> 4;
    const int c    = lane & 15;
    const int cq   = c & 7;

    __shared__ __align__(16) bf16_t ys[32 * 512];   // 32KB [row][1024B], swizzled

    {
        const int hsel = lane >> 3;
        const int g7   = lane & 7;
        #pragma unroll
        for (int rr = 0; rr < 8; ++rr) {
            int row = w * 8 + rr;
            const char* src = (const char*)y
                + (((size_t)b * HH + hsel) * NN + nn0 + row) * 128
                + ((g7 ^ (row & 7)) * 16);
            dma16(src, (char*)ys + row * 1024);
        }
    }
    __syncthreads();

    const int rows16 = (w >> 1) * 16;
    const int mb     = dh * 2 + (w & 1);
    const char* yrow = (const char*)ys + (rows16 + c) * 1024;

    f32x4 acc = (f32x4){0.f, 0.f, 0.f, 0.f};
    #pragma unroll
    for (int kk = 0; kk < 16; ++kk) {
        int g = kk * 4 + quad;
        bf16x8 bfrag = *(const bf16x8*)(yrow + (((g & ~7) | ((g & 7) ^ cq)) * 16));
        bf16x8 afrag = *(const bf16x8*)((const char*)Wut
                        + (size_t)(mb * 16 + c) * 1024 + kk * 64 + quad * 16);
        acc = MFMA(afrag, bfrag, acc, 0, 0, 0);
    }

    float4 bb = *(const float4*)(bu + mb * 16 + quad * 4);
    float4 res = { acc[0] + bb.x, acc[1] + bb.y, acc[2] + bb.z, acc[3] + bb.w };
    float* op = out + (size_t)(row0 + rows16 + c) * DD + mb * 16 + quad * 4;
    *(float4*)op = res;
}

// -------------------------------------------------------------------------
extern "C" void kernel_launch(void* const* d_in, const int* in_sizes, int n_in,
                              void* d_out, int out_size, void* d_ws, size_t ws_size,
                              hipStream_t stream) {
    const float* x  = (const float*)d_in[0];
    const float* Wq = (const float*)d_in[1];
    const float* Wk = (const float*)d_in[2];
    const float* Wv = (const float*)d_in[3];
    const float* Wu = (const float*)d_in[4];
    const float* bu = (const float*)d_in[5];
    float* out = (float*)d_out;

    // workspace: q8 4M | k8 4M | vt 8M (f16) | y 8M (bf16) | weights 64K x4
    const size_t SEG8 = (size_t)BB * HH * NN * 64;   // 4 MiB (fp8 rows)
    const size_t SEG  = SEG8 * 2;                    // 8 MiB
    char* ws = (char*)d_ws;
    char*   q8  = ws;
    char*   k8  = ws + SEG8;
    f16_t*  vt  = (f16_t*)(ws + 2 * SEG8);
    bf16_t* y   = (bf16_t*)(ws + 2 * SEG8 + SEG);
    bf16_t* Wqt = (bf16_t*)(ws + 2 * SEG8 + 2 * SEG);
    bf16_t* Wkt = (bf16_t*)(ws + 2 * SEG8 + 2 * SEG + (1 << 16));
    bf16_t* Wvt = (bf16_t*)(ws + 2 * SEG8 + 2 * SEG + 2 * (1 << 16));
    bf16_t* Wut = (bf16_t*)(ws + 2 * SEG8 + 2 * SEG + 3 * (1 << 16));

    prep<<<dim3(16), dim3(256), 0, stream>>>(Wq, Wk, Wv, Wu, Wqt, Wkt, Wvt, Wut);
    qkv_mfma<<<dim3(128, 8), dim3(256), 0, stream>>>(x, Wqt, Wkt, Wvt, q8, k8, vt);
    flash_attn<<<dim3(HH, NN / 128, BB), dim3(512), 0, stream>>>(q8, k8, vt, y);
    out_proj<<<dim3(512), dim3(256), 0, stream>>>(y, Wut, bu, out);
}

// Round 7
// 126.375 us; speedup vs baseline: 1.1216x; 1.0129x over previous
//
#include <hip/hip_runtime.h>
#include <hip/hip_bf16.h>

// Problem constants
#define BB 4
#define NN 2048
#define DD 64
#define HH 8
#define DHH 512  // D*H

typedef __bf16 bf16_t;
typedef __bf16 bf16x8 __attribute__((ext_vector_type(8)));
typedef __bf16 bf16x4 __attribute__((ext_vector_type(4)));
typedef float f32x4 __attribute__((ext_vector_type(4)));
typedef long long i64;
typedef i64 i64x2 __attribute__((ext_vector_type(2)));
typedef _Float16 f16_t;
typedef _Float16 f16x4 __attribute__((ext_vector_type(4)));
typedef __fp16 h16x2 __attribute__((ext_vector_type(2)));   // cvt_pkrtz native type

// Async global->LDS, 16B per lane. HW places lane i at (wave-uniform base) + i*16.
__device__ __forceinline__ void dma16(const void* g, void* l) {
    __builtin_amdgcn_global_load_lds(
        (const __attribute__((address_space(1))) unsigned int*)g,
        (__attribute__((address_space(3))) unsigned int*)l,
        16, 0, 0);
}

#define MFMA   __builtin_amdgcn_mfma_f32_16x16x32_bf16
#define MFMA8  __builtin_amdgcn_mfma_f32_16x16x32_fp8_fp8
#define MFMA16F __builtin_amdgcn_mfma_f32_16x16x16f16

// q-scale 1/sqrt(64) with log2(e) folded in (softmax via exp2)
#define QSCALE 0.18033688011112042f

// fp8 q/k row layout (64 bytes per (b,h,n)): logical element d lives at byte
//   phys(d) = (d&7) + (d>>5)*8 + (((d>>3)&3) ^ swz2(n))*16,  swz2(n) = (n&3)^((n>>2)&3)
// One b128 read at granule (quad ^ swz2(n)) yields BOTH K=32 fp8 MFMA frags
// (i64x2: .x = k-lo, .y = k-hi). Widened swz2 -> K ds_read_b128 conflict-free.
//
// vt layout: [b, h, kb=n>>4, q2=(n>>2)&3, d, n&3] f16 — each 16-key block is
// a contiguous 2KB slice; V ds_read_b64 at quad*512 + db*128 + c*8 is
// conflict-free.
//
// R7 flash: staging is fully WAVE-PRIVATE (since R5) -> the in-loop
// __syncthreads was only serving as a vmcnt(0) drain. Replace it with
// per-wave COUNTED s_waitcnt vmcnt(6) (T4): the fresh prefetch stays in
// flight, no cross-wave convergence, no drain-to-0 until the tail.
// Single __syncthreads before the epilogue LDS overlay (the only real
// cross-wave exchange).

// -------------------------------------------------------------------------
// Kernel P: prep — widened to 64 blocks (R7). Wqt/Wkt/Wvt [512][64] bf16
// (QSCALE in Wqt), Wut [64][512] bf16.
// -------------------------------------------------------------------------
__global__ __launch_bounds__(256) void prep(
    const float* __restrict__ Wq, const float* __restrict__ Wk,
    const float* __restrict__ Wv, const float* __restrict__ Wu,
    bf16_t* __restrict__ Wqt, bf16_t* __restrict__ Wkt,
    bf16_t* __restrict__ Wvt, bf16_t* __restrict__ Wut)
{
    const int bid = blockIdx.x, tid = threadIdx.x;
    if (bid < 48) {
        const int m = bid >> 4, slice = bid & 15;
        const float* src = (m == 0) ? Wq : (m == 1) ? Wk : Wv;
        bf16_t* dst = (m == 0) ? Wqt : (m == 1) ? Wkt : Wvt;
        const float scale = (m == 0) ? QSCALE : 1.0f;
        const int dc = slice * 32 + (tid >> 3);
        const int kbase = (tid & 7) * 8;
        bf16x8 p;
        #pragma unroll
        for (int j = 0; j < 8; ++j)
            p[j] = (bf16_t)(src[(size_t)(kbase + j) * 512 + dc] * scale);
        *(bf16x8*)(dst + dc * 64 + kbase) = p;
    } else {
        const int kq = (bid - 48) * 32;
        const int dc = tid >> 2, sub = (tid & 3) * 8;
        bf16x8 p;
        #pragma unroll
        for (int j = 0; j < 8; ++j)
            p[j] = (bf16_t)Wu[(size_t)(kq + sub + j) * 64 + dc];
        *(bf16x8*)(Wut + dc * 512 + kq + sub) = p;
    }
}

// -------------------------------------------------------------------------
// Kernel A: QKV via MFMA (unchanged — verified). q,k -> fp8 e4m3 packed
// (widened swz2); vt -> f16 [b,h,kb,q2,d,klow].
// -------------------------------------------------------------------------
__global__ __launch_bounds__(256) void qkv_mfma(
    const float* __restrict__ x, const bf16_t* __restrict__ Wqt,
    const bf16_t* __restrict__ Wkt, const bf16_t* __restrict__ Wvt,
    char* __restrict__ q8, char* __restrict__ k8, f16_t* __restrict__ vt)
{
    const int n0   = blockIdx.x * 64;
    const int h    = blockIdx.y;
    const int tid  = threadIdx.x;
    const int w    = tid >> 6;
    const int lane = tid & 63;
    const int quad = lane >> 4;
    const int c    = lane & 15;
    const int cq   = c & 7;
    const int l8   = lane >> 3;
    const int lg   = (lane & 7) ^ l8;
    const int lo   = l8 * 128 + lg * 16;
    const int sw0  = ((quad    ) ^ cq) * 16;
    const int sw1  = ((quad + 4) ^ cq) * 16;
    const int w2048 = w * 2048;

    __shared__ __align__(16) float  xs[64 * 64];   // 16KB [row][256B], swizzled
    __shared__ __align__(16) bf16_t Wqs[64 * 64], Wks[64 * 64], Wvs[64 * 64];

    {
        const int rloc = lane >> 4;
        const int s    = lane & 15;
        #pragma unroll
        for (int j = 0; j < 4; ++j) {
            int chunk = w * 4 + j;
            int r7 = (chunk * 4 + rloc) & 7;
            const char* src = (const char*)(x + (size_t)(n0 + chunk * 4 + rloc) * 64)
                            + ((s & 8) | ((s & 7) ^ r7)) * 16;
            dma16(src, (char*)xs + chunk * 1024);
        }
    }
    const char* qg = (const char*)Wqt + (size_t)h * 8192;
    const char* kg = (const char*)Wkt + (size_t)h * 8192;
    const char* vg = (const char*)Wvt + (size_t)h * 8192;
    dma16(qg + w2048 + lo,        (char*)Wqs + w2048);
    dma16(qg + w2048 + 1024 + lo, (char*)Wqs + w2048 + 1024);
    dma16(kg + w2048 + lo,        (char*)Wks + w2048);
    dma16(kg + w2048 + 1024 + lo, (char*)Wks + w2048 + 1024);
    dma16(vg + w2048 + lo,        (char*)Wvs + w2048);
    dma16(vg + w2048 + 1024 + lo, (char*)Wvs + w2048 + 1024);
    __syncthreads();

    auto xfrag = [&](int row, int kk) -> bf16x8 {
        const char* rbase = (const char*)xs + row * 256;
        int g0 = kk * 8 + ((quad * 2    ) ^ cq);
        int g1 = kk * 8 + ((quad * 2 + 1) ^ cq);
        f32x4 a = *(const f32x4*)(rbase + g0 * 16);
        f32x4 b = *(const f32x4*)(rbase + g1 * 16);
        bf16x8 r;
        r[0] = (bf16_t)a[0]; r[1] = (bf16_t)a[1]; r[2] = (bf16_t)a[2]; r[3] = (bf16_t)a[3];
        r[4] = (bf16_t)b[0]; r[5] = (bf16_t)b[1]; r[6] = (bf16_t)b[2]; r[7] = (bf16_t)b[3];
        return r;
    };

    bf16x8 xf0 = xfrag(w * 16 + c, 0);
    bf16x8 xf1 = xfrag(w * 16 + c, 1);

    const int gr = n0 + w * 16 + c;
    const int bb = gr >> 11, nn = gr & 2047;
    char* qrow_g = q8 + (((size_t)bb * HH + h) * NN + nn) * 64;
    char* krow_g = k8 + (((size_t)bb * HH + h) * NN + nn) * 64;
    const int nsw = (nn & 3) ^ ((nn >> 2) & 3);   // widened granule swizzle

    #pragma unroll
    for (int mb = 0; mb < 4; ++mb) {
        const char* aq = (const char*)Wqs + (mb * 16 + c) * 128;
        const char* ak = (const char*)Wks + (mb * 16 + c) * 128;
        f32x4 accq = (f32x4){0.f, 0.f, 0.f, 0.f};
        f32x4 acck = (f32x4){0.f, 0.f, 0.f, 0.f};
        accq = MFMA(*(const bf16x8*)(aq + sw0), xf0, accq, 0, 0, 0);
        accq = MFMA(*(const bf16x8*)(aq + sw1), xf1, accq, 0, 0, 0);
        acck = MFMA(*(const bf16x8*)(ak + sw0), xf0, acck, 0, 0, 0);
        acck = MFMA(*(const bf16x8*)(ak + sw1), xf1, acck, 0, 0, 0);
        int g2  = (mb * 2 + (quad >> 1)) & 3;
        int off = ((quad & 1) * 4) + ((mb >> 1) * 8) + ((g2 ^ nsw) * 16);
        int pq = __builtin_amdgcn_cvt_pk_fp8_f32(accq[0], accq[1], 0, false);
        pq     = __builtin_amdgcn_cvt_pk_fp8_f32(accq[2], accq[3], pq, true);
        int pk = __builtin_amdgcn_cvt_pk_fp8_f32(acck[0], acck[1], 0, false);
        pk     = __builtin_amdgcn_cvt_pk_fp8_f32(acck[2], acck[3], pk, true);
        *(int*)(qrow_g + off) = pq;
        *(int*)(krow_g + off) = pk;
    }

    const char* wvrow = (const char*)Wvs + (w * 16 + c) * 128;
    bf16x8 vf0 = *(const bf16x8*)(wvrow + sw0);
    bf16x8 vf1 = *(const bf16x8*)(wvrow + sw1);

    const int bb2 = n0 >> 11;
    // vt [b,h,kb,q2,d,klow]: lane (quad,c) acc j = V^T[d=w*16+c][k=nb*16+quad*4+j]
    f16_t* vtb = vt + ((size_t)bb2 * HH + h) * (size_t)(DD * NN)
               + (size_t)((n0 & 2047) >> 4) * 1024 + quad * 256 + (w * 16 + c) * 4;

    #pragma unroll
    for (int nb = 0; nb < 4; ++nb) {
        f32x4 acc = (f32x4){0.f, 0.f, 0.f, 0.f};
        acc = MFMA(xfrag(nb * 16 + c, 0), vf0, acc, 0, 0, 0);
        acc = MFMA(xfrag(nb * 16 + c, 1), vf1, acc, 0, 0, 0);
        f16x4 p = { (f16_t)acc[0], (f16_t)acc[1], (f16_t)acc[2], (f16_t)acc[3] };
        *(f16x4*)(vtb + nb * 1024) = p;
    }
}

// -------------------------------------------------------------------------
// Kernel B: flash attention — R7: R5's exact layouts/macros/epilogue with
// the in-loop __syncthreads replaced by per-wave counted s_waitcnt vmcnt.
// Valid because staging is wave-private (wave w writes/reads only its own
// LDS slices). Schedule per wave:
//   S(0); vmcnt(0); S(1);
//   loop p: BODY(p); [sched_barrier] S(p+2) -> vmcnt(6)  (waits S(p+1),
//           leaves S(p+2) in flight; in-order vmcnt retirement, m135)
//   tail p=14: vmcnt(0) (S(15) done), p=15: no wait.
// WAW safe: BODY(p)'s ds_reads retire (compiler lgkmcnt before dependent
// MFMAs) before S(p+2) — same-iteration program order + sched_barrier(0).
// One __syncthreads before the epilogue overlay (only cross-wave exchange).
// -------------------------------------------------------------------------
__global__ __launch_bounds__(256, 3) void flash_attn(
    const char* __restrict__ q8, const char* __restrict__ k8,
    const f16_t* __restrict__ vt, bf16_t* __restrict__ y)
{
    const int h    = blockIdx.x;          // head first -> XCD L2 locality
    const int n0   = blockIdx.y * 64;
    const int b    = blockIdx.z;
    const int tid  = threadIdx.x;
    const int w    = tid >> 6;
    const int lane = tid & 63;
    const int quad = lane >> 4;
    const int c    = lane & 15;
    const int ksw  = (quad ^ (c & 3) ^ ((c >> 2) & 3)) * 16;  // widened fp8 swz

    __shared__ __align__(16) char SM[49152];   // 2 x 24KB; epilogue overlay 17KB

    const size_t bh = (size_t)(b * HH + h);
    const char* qp = q8 + bh * (size_t)(NN * 64);
    const char* kp = k8 + bh * (size_t)(NN * 64);
    const char* vp = (const char*)(vt + bh * (size_t)(DD * NN));

    // Q B-frags (fp8 packed)
    i64x2 qf[4];
    #pragma unroll
    for (int cb = 0; cb < 4; ++cb)
        qf[cb] = *(const i64x2*)(qp + (size_t)(n0 + cb * 16 + c) * 64 + ksw);

    // DMA source lane pointers (wave-private contiguous slices)
    const char* kdma = kp + w * 1024 + lane * 16;   // + tile*4096
    const char* vdma = vp + w * 2048 + lane * 16;   // + tile*8192

    // LDS read offsets (within 24KB buffer)
    const int kro = w * 2048 + c * 64 + ksw;
    const int vro = 8192 + w * 4096 + quad * 512 + c * 8;

    f32x4 lsum4[4];
    f32x4 o[4][4];   // o[db][cb]: O^T[d=db*16+quad*4+r][q=cb*16+c]
    #pragma unroll
    for (int cb = 0; cb < 4; ++cb) lsum4[cb] = (f32x4){0.f, 0.f, 0.f, 0.f};
    #pragma unroll
    for (int db = 0; db < 4; ++db)
        #pragma unroll
        for (int cb = 0; cb < 4; ++cb) o[db][cb] = (f32x4){0.f, 0.f, 0.f, 0.f};

    // Stage phase p (tiles 2p, 2p+1) into buffer buf: 6 dma16 per wave.
    #define STAGE2(p, buf) do {                                               \
        char* B_ = SM + (buf) * 24576;                                        \
        const size_t t0_ = (size_t)(2 * (p));                                 \
        dma16(kdma + t0_ * 4096,         B_ + w * 2048);                      \
        dma16(kdma + t0_ * 4096 + 4096,  B_ + w * 2048 + 1024);               \
        dma16(vdma + t0_ * 8192,         B_ + 8192 + w * 4096);               \
        dma16(vdma + t0_ * 8192 + 1024,  B_ + 8192 + w * 4096 + 1024);        \
        dma16(vdma + t0_ * 8192 + 8192,  B_ + 8192 + w * 4096 + 2048);        \
        dma16(vdma + t0_ * 8192 + 9216,  B_ + 8192 + w * 4096 + 3072);        \
    } while (0)

    // Compute one tile (half hf of buffer buf) — identical to R5.
    #define BODY2(buf, hf) do {                                               \
        const char* kb_b = SM + (buf) * 24576;                                \
        i64x2 kf_ = *(const i64x2*)(kb_b + kro + (hf) * 1024);                \
        f16x4 vf_[4];                                                         \
        _Pragma("unroll")                                                     \
        for (int db = 0; db < 4; ++db)                                        \
            vf_[db] = *(const f16x4*)(kb_b + vro + (hf) * 2048 + db * 128);   \
        _Pragma("unroll")                                                     \
        for (int cb = 0; cb < 4; ++cb) {                                      \
            f32x4 s_ = (f32x4){0.f, 0.f, 0.f, 0.f};                           \
            s_ = MFMA8(kf_.x, qf[cb].x, s_, 0, 0, 0);                         \
            s_ = MFMA8(kf_.y, qf[cb].y, s_, 0, 0, 0);                         \
            float p0_ = __builtin_amdgcn_exp2f(s_[0]);                        \
            float p1_ = __builtin_amdgcn_exp2f(s_[1]);                        \
            float p2_ = __builtin_amdgcn_exp2f(s_[2]);                        \
            float p3_ = __builtin_amdgcn_exp2f(s_[3]);                        \
            lsum4[cb] += (f32x4){p0_, p1_, p2_, p3_};                         \
            h16x2 ab_ = __builtin_amdgcn_cvt_pkrtz(p0_, p1_);                 \
            h16x2 cd_ = __builtin_amdgcn_cvt_pkrtz(p2_, p3_);                 \
            f16x4 pf_;                                                        \
            __builtin_memcpy(&pf_, &ab_, 4);                                  \
            __builtin_memcpy((char*)&pf_ + 4, &cd_, 4);                       \
            _Pragma("unroll")                                                 \
            for (int db = 0; db < 4; ++db)                                    \
                o[db][cb] = MFMA16F(vf_[db], pf_, o[db][cb], 0, 0, 0);        \
        }                                                                     \
    } while (0)

    // Prologue: stage phase 0, per-wave drain, prefetch phase 1.
    STAGE2(0, 0);
    asm volatile("s_waitcnt vmcnt(0)" ::: "memory");
    __builtin_amdgcn_sched_barrier(0);
    STAGE2(1, 1);

    #pragma unroll 1
    for (int p = 0; p < 16; ++p) {
        BODY2(p & 1, 0);
        BODY2(p & 1, 1);
        if (p < 15) {
            __builtin_amdgcn_sched_barrier(0);   // pin BODY's ds_reads above refill
            if (p < 14) {
                STAGE2(p + 2, p & 1);            // refill just-consumed buffer
                asm volatile("s_waitcnt vmcnt(6)" ::: "memory");  // S(p+1) done
            } else {
                asm volatile("s_waitcnt vmcnt(0)" ::: "memory");  // S(15) done
            }
            __builtin_amdgcn_sched_barrier(0);   // pin next BODY below the wait
        }
    }

    #undef STAGE2
    #undef BODY2

    // horizontal lsum
    float lsum[4];
    #pragma unroll
    for (int cb = 0; cb < 4; ++cb)
        lsum[cb] = (lsum4[cb][0] + lsum4[cb][1]) + (lsum4[cb][2] + lsum4[cb][3]);

    __syncthreads();   // re-converge waves before LDS overlay reuse

    // ---- epilogue: cross-wave reduction (Ob = SM[0..16K), Lb = SM+16K) ----
    char*  Ob = SM;
    float* Lb = (float*)(SM + 16384);

    #pragma unroll
    for (int cb = 0; cb < 4; ++cb) {
        lsum[cb] += __shfl_xor(lsum[cb], 16, 64);
        lsum[cb] += __shfl_xor(lsum[cb], 32, 64);
    }
    if (quad == 0) {
        #pragma unroll
        for (int cb = 0; cb < 4; ++cb)
            Lb[(w * 4 + cb) * 16 + c] = lsum[cb];
    }

    // O: sequential accumulate across waves
    #pragma unroll
    for (int ww = 0; ww < 4; ++ww) {
        if (w == ww) {
            #pragma unroll
            for (int db = 0; db < 4; ++db) {
                #pragma unroll
                for (int cb = 0; cb < 4; ++cb) {
                    char* p = Ob + (size_t)(((db * 4 + cb) * 4 + quad) * 16 + c) * 16;
                    f32x4 v = o[db][cb];
                    if (ww > 0) v += *(const f32x4*)p;
                    *(f32x4*)p = v;
                }
            }
        }
        __syncthreads();
    }

    // readout: thread t -> q-row n_loc = t&63, d-quarter dq = t>>6
    {
        const int n_loc = tid & 63;
        const int dq    = tid >> 6;
        const int qcb   = n_loc >> 4;
        const int cc    = n_loc & 15;
        float l = Lb[(0 * 4 + qcb) * 16 + cc] + Lb[(1 * 4 + qcb) * 16 + cc]
                + Lb[(2 * 4 + qcb) * 16 + cc] + Lb[(3 * 4 + qcb) * 16 + cc];
        float inv = 1.0f / l;
        float vals[16];
        #pragma unroll
        for (int q2 = 0; q2 < 4; ++q2) {
            f32x4 v = *(const f32x4*)(Ob
                    + (size_t)(((dq * 4 + qcb) * 4 + q2) * 16 + cc) * 16);
            vals[q2 * 4 + 0] = v[0]; vals[q2 * 4 + 1] = v[1];
            vals[q2 * 4 + 2] = v[2]; vals[q2 * 4 + 3] = v[3];
        }
        bf16x8 o0, o1;
        #pragma unroll
        for (int j = 0; j < 8; ++j) {
            o0[j] = (bf16_t)(vals[j] * inv);
            o1[j] = (bf16_t)(vals[8 + j] * inv);
        }
        bf16_t* yrow = y + bh * (size_t)(NN * DD) + (size_t)(n0 + n_loc) * DD + dq * 16;
        *(bf16x8*)(yrow)     = o0;
        *(bf16x8*)(yrow + 8) = o1;
    }
}

// -------------------------------------------------------------------------
// Kernel C: output projection via MFMA (unchanged). 512 blocks.
// -------------------------------------------------------------------------
__global__ __launch_bounds__(256) void out_proj(
    const bf16_t* __restrict__ y,    // [b,h,n,d] bf16
    const bf16_t* __restrict__ Wut,  // [64][512]
    const float* __restrict__ bu, float* __restrict__ out)
{
    const int rt   = blockIdx.x >> 1;
    const int dh   = blockIdx.x & 1;
    const int row0 = rt * 32;
    const int b    = row0 >> 11;
    const int nn0  = row0 & 2047;
    const int tid  = threadIdx.x;
    const int w    = tid >> 6;
    const int lane = tid & 63;
    const int quad = lane >> 4;
    const int c    = lane & 15;
    const int cq   = c & 7;

    __shared__ __align__(16) bf16_t ys[32 * 512];   // 32KB [row][1024B], swizzled

    {
        const int hsel = lane >> 3;
        const int g7   = lane & 7;
        #pragma unroll
        for (int rr = 0; rr < 8; ++rr) {
            int row = w * 8 + rr;
            const char* src = (const char*)y
                + (((size_t)b * HH + hsel) * NN + nn0 + row) * 128
                + ((g7 ^ (row & 7)) * 16);
            dma16(src, (char*)ys + row * 1024);
        }
    }
    __syncthreads();

    const int rows16 = (w >> 1) * 16;
    const int mb     = dh * 2 + (w & 1);
    const char* yrow = (const char*)ys + (rows16 + c) * 1024;

    f32x4 acc = (f32x4){0.f, 0.f, 0.f, 0.f};
    #pragma unroll
    for (int kk = 0; kk < 16; ++kk) {
        int g = kk * 4 + quad;
        bf16x8 bfrag = *(const bf16x8*)(yrow + (((g & ~7) | ((g & 7) ^ cq)) * 16));
        bf16x8 afrag = *(const bf16x8*)((const char*)Wut
                        + (size_t)(mb * 16 + c) * 1024 + kk * 64 + quad * 16);
        acc = MFMA(afrag, bfrag, acc, 0, 0, 0);
    }

    float4 bb = *(const float4*)(bu + mb * 16 + quad * 4);
    float4 res = { acc[0] + bb.x, acc[1] + bb.y, acc[2] + bb.z, acc[3] + bb.w };
    float* op = out + (size_t)(row0 + rows16 + c) * DD + mb * 16 + quad * 4;
    *(float4*)op = res;
}

// -------------------------------------------------------------------------
extern "C" void kernel_launch(void* const* d_in, const int* in_sizes, int n_in,
                              void* d_out, int out_size, void* d_ws, size_t ws_size,
                              hipStream_t stream) {
    const float* x  = (const float*)d_in[0];
    const float* Wq = (const float*)d_in[1];
    const float* Wk = (const float*)d_in[2];
    const float* Wv = (const float*)d_in[3];
    const float* Wu = (const float*)d_in[4];
    const float* bu = (const float*)d_in[5];
    float* out = (float*)d_out;

    // workspace: q8 4M | k8 4M | vt 8M (f16) | y 8M (bf16) | weights 64K x4
    const size_t SEG8 = (size_t)BB * HH * NN * 64;   // 4 MiB (fp8 rows)
    const size_t SEG  = SEG8 * 2;                    // 8 MiB
    char* ws = (char*)d_ws;
    char*   q8  = ws;
    char*   k8  = ws + SEG8;
    f16_t*  vt  = (f16_t*)(ws + 2 * SEG8);
    bf16_t* y   = (bf16_t*)(ws + 2 * SEG8 + SEG);
    bf16_t* Wqt = (bf16_t*)(ws + 2 * SEG8 + 2 * SEG);
    bf16_t* Wkt = (bf16_t*)(ws + 2 * SEG8 + 2 * SEG + (1 << 16));
    bf16_t* Wvt = (bf16_t*)(ws + 2 * SEG8 + 2 * SEG + 2 * (1 << 16));
    bf16_t* Wut = (bf16_t*)(ws + 2 * SEG8 + 2 * SEG + 3 * (1 << 16));

    prep<<<dim3(64), dim3(256), 0, stream>>>(Wq, Wk, Wv, Wu, Wqt, Wkt, Wvt, Wut);
    qkv_mfma<<<dim3(128, 8), dim3(256), 0, stream>>>(x, Wqt, Wkt, Wvt, q8, k8, vt);
    flash_attn<<<dim3(HH, NN / 64, BB), dim3(256), 0, stream>>>(q8, k8, vt, y);
    out_proj<<<dim3(512), dim3(256), 0, stream>>>(y, Wut, bu, out);
}